// Round 9
// baseline (324.600 us; speedup 1.0000x reference)
//
#include <hip/hip_runtime.h>
#include <hip/hip_bf16.h>

typedef __hip_bfloat16 bf16;
typedef short bf16x8 __attribute__((ext_vector_type(8)));
typedef float f32x4 __attribute__((ext_vector_type(4)));

constexpr int Bb = 16, Nn = 1024, Cc = 768, Dd = 384;

static __device__ __forceinline__ f32x4 mfma16(bf16x8 a, bf16x8 b, f32x4 c) {
    return __builtin_amdgcn_mfma_f32_16x16x32_bf16(a, b, c, 0, 0, 0);
}
static __device__ __forceinline__ short f2b(float v) {
    __hip_bfloat16 h = __float2bfloat16(v);
    return *reinterpret_cast<short*>(&h);
}
static __device__ __forceinline__ unsigned pack2(float lo, float hi) {
    return ((unsigned)(unsigned short)f2b(hi) << 16) | (unsigned short)(unsigned)f2b(lo);
}
static __device__ __forceinline__ float b2f(bf16 x) { return __bfloat162float(x); }

// async 16B global->LDS (gfx950). lds base must be wave-uniform; lane writes
// base + lane*16. global src is per-lane.
#define GLOAD_LDS16(g, l) __builtin_amdgcn_global_load_lds(                    \
    (const __attribute__((address_space(1))) void*)(g),                        \
    (__attribute__((address_space(3))) void*)(l), 16, 0, 0)

// -------- x f32 -> bf16 cast (one pass) + bias concat folded into block 0 ----
__global__ __launch_bounds__(256) void cast_bias(
    const float* __restrict__ in, uint4* __restrict__ out,
    const float* __restrict__ bt, const float* __restrict__ bp,
    const float* __restrict__ bg, float* __restrict__ biasP)
{
    const size_t i = (size_t)blockIdx.x * 256 + threadIdx.x;
    const float4 a = reinterpret_cast<const float4*>(in)[i * 2];
    const float4 b = reinterpret_cast<const float4*>(in)[i * 2 + 1];
    uint4 v;
    v.x = pack2(a.x, a.y);
    v.y = pack2(a.z, a.w);
    v.z = pack2(b.x, b.y);
    v.w = pack2(b.z, b.w);
    out[i] = v;
    if (blockIdx.x == 0) {
        for (int k = threadIdx.x; k < 1152; k += 256)
            biasP[k] = k < 384 ? bt[k] : (k < 768 ? bp[k - 384] : bg[k - 768]);
    }
}

// ---------------- transpose + cast: out[n][k] = (bf16) in[k][n] ---------------
__global__ __launch_bounds__(256) void transpose_cast(
    const float* __restrict__ in, bf16* __restrict__ out, int K, int N)
{
    __shared__ float t[32][33];
    const int n0 = blockIdx.x * 32, k0 = blockIdx.y * 32;
    const int tx = threadIdx.x & 31, ty = threadIdx.x >> 5;
#pragma unroll
    for (int i = 0; i < 4; i++)
        t[ty + i * 8][tx] = in[(size_t)(k0 + ty + i * 8) * N + n0 + tx];
    __syncthreads();
#pragma unroll
    for (int i = 0; i < 4; i++)
        out[(size_t)(n0 + ty + i * 8) * K + k0 + tx] = __float2bfloat16(t[tx][ty + i * 8]);
}

// -------- 3x QKV weight transpose in one launch (blockIdx.z selects) ---------
__global__ __launch_bounds__(256) void transpose_cast3(
    const float* __restrict__ w0, const float* __restrict__ w1,
    const float* __restrict__ w2, bf16* __restrict__ outbase)
{
    __shared__ float t[32][33];
    const float* in = blockIdx.z == 0 ? w0 : (blockIdx.z == 1 ? w1 : w2);
    bf16* out = outbase + (size_t)blockIdx.z * Cc * Dd;
    const int n0 = blockIdx.x * 32, k0 = blockIdx.y * 32;
    const int tx = threadIdx.x & 31, ty = threadIdx.x >> 5;
#pragma unroll
    for (int i = 0; i < 4; i++)
        t[ty + i * 8][tx] = in[(size_t)(k0 + ty + i * 8) * Dd + n0 + tx];
    __syncthreads();
#pragma unroll
    for (int i = 0; i < 4; i++)
        out[(size_t)(n0 + ty + i * 8) * Cc + k0 + tx] = __float2bfloat16(t[tx][ty + i * 8]);
}

// ======= bf16 MFMA GEMM v2: global_load_lds staging, BK=64, XOR swizzle ======
// C = A[M,K] @ BT[N,K]^T + bias. 128x128 tile, 256 threads (4 waves, 64x64).
// LDS linear [128 rows][64 shorts]; slot ch of row r holds global chunk
// ch ^ (r&7). Both-sides swizzle via pre-swizzled per-lane global source.
// EPI: 2 = f32 out with +resid; 3 = fused projection split (theta|phi|gT).
template <int EPI>
__global__ __launch_bounds__(256) void gemm_bf16(
    const bf16* __restrict__ A, const bf16* __restrict__ BT,
    const float* __restrict__ bias, const float* __restrict__ resid,
    void* __restrict__ outp, int K, int Nout)
{
    __shared__ short As[128 * 64];
    __shared__ short Bs[128 * 64];
    const int tid = threadIdx.x;
    const int lane = tid & 63, w = tid >> 6;
    const int quad = lane >> 4, c = lane & 15;
    const int row0 = blockIdx.x * 128, col0 = blockIdx.y * 128;
    const int wm = (w & 1) * 64, wn = (w >> 1) * 64;

    const int rA = w * 32 + (lane >> 3);
    const int cs = (lane & 7) ^ (lane >> 3);
    const bf16* Ag = A  + (size_t)(row0 + rA) * K + cs * 8;
    const bf16* Bg = BT + (size_t)(col0 + rA) * K + cs * 8;
    char* Asb = (char*)As + w * 4096;
    char* Bsb = (char*)Bs + w * 4096;

    const f32x4 fz = {0.f, 0.f, 0.f, 0.f};
    f32x4 acc[4][4];
#pragma unroll
    for (int i = 0; i < 4; i++)
#pragma unroll
        for (int j = 0; j < 4; j++) acc[i][j] = fz;

    for (int k0 = 0; k0 < K; k0 += 64) {
        __syncthreads();
#pragma unroll
        for (int i = 0; i < 4; i++) {
            GLOAD_LDS16(Ag + (size_t)i * 8 * K + k0, Asb + i * 1024);
            GLOAD_LDS16(Bg + (size_t)i * 8 * K + k0, Bsb + i * 1024);
        }
        __syncthreads();   // compiler drains vmcnt before barrier

        bf16x8 af[2][4], bfr[2][4];
#pragma unroll
        for (int kk = 0; kk < 2; kk++) {
#pragma unroll
            for (int i = 0; i < 4; i++) {
                const int r = wm + i * 16 + c;
                const int ch = (kk * 4 + quad) ^ (r & 7);
                af[kk][i] = *reinterpret_cast<const bf16x8*>(&As[r * 64 + ch * 8]);
            }
#pragma unroll
            for (int j = 0; j < 4; j++) {
                const int r = wn + j * 16 + c;
                const int ch = (kk * 4 + quad) ^ (r & 7);
                bfr[kk][j] = *reinterpret_cast<const bf16x8*>(&Bs[r * 64 + ch * 8]);
            }
        }
#pragma unroll
        for (int kk = 0; kk < 2; kk++)
#pragma unroll
            for (int i = 0; i < 4; i++)
#pragma unroll
                for (int j = 0; j < 4; j++)
                    acc[i][j] = mfma16(af[kk][i], bfr[kk][j], acc[i][j]);
    }

    const size_t SZc = (size_t)Bb * Nn * Dd;
#pragma unroll
    for (int i = 0; i < 4; i++) {
        const int rowb = row0 + wm + i * 16 + quad * 4;
#pragma unroll
        for (int j = 0; j < 4; j++) {
            const int col = col0 + wn + j * 16 + c;
            const float bcol = bias[col];
#pragma unroll
            for (int r = 0; r < 4; r++) {
                float v = acc[i][j][r] + bcol;
                const int rr = rowb + r;
                if (EPI == 2) {
                    v += resid[(size_t)rr * Nout + col];
                    ((float*)outp)[(size_t)rr * Nout + col] = v;
                } else {
                    // fused projection: col 0..383 theta, 384..767 phi, 768.. gT
                    const int seg = col / 384;
                    const int cl = col - seg * 384;
                    bf16* base = (bf16*)outp;
                    if (seg < 2) {
                        base[(size_t)seg * SZc + (size_t)rr * Dd + cl] = __float2bfloat16(v);
                    } else {
                        const int bb = rr >> 10, m = rr & 1023;
                        base[2 * SZc + ((size_t)(bb * Dd + cl)) * 1024 + m] = __float2bfloat16(v);
                    }
                }
            }
        }
    }
}

// ---------------- MFMA GEMM v1 (reg-staged) — fallback paths only ------------
template <typename TA, int EPI>
__global__ __launch_bounds__(256) void gemm_mfma(
    const TA* __restrict__ A, const bf16* __restrict__ BT,
    const float* __restrict__ bias, const float* __restrict__ resid,
    void* __restrict__ outp, int K, int Nout)
{
    __shared__ short As[128 * 40];
    __shared__ short Bs[128 * 40];
    const int tid = threadIdx.x;
    const int lane = tid & 63, w = tid >> 6;
    const int quad = lane >> 4, c = lane & 15;
    const int row0 = blockIdx.x * 128, col0 = blockIdx.y * 128;
    const int wm = (w & 1) * 64, wn = (w >> 1) * 64;

    const f32x4 fz = {0.f, 0.f, 0.f, 0.f};
    f32x4 acc[4][4];
#pragma unroll
    for (int i = 0; i < 4; i++)
#pragma unroll
        for (int j = 0; j < 4; j++) acc[i][j] = fz;

    for (int k0 = 0; k0 < K; k0 += 32) {
        __syncthreads();
        if (sizeof(TA) == 4) {
            const float* Af = (const float*)A;
#pragma unroll
            for (int u = 0; u < 4; u++) {
                const int id = u * 256 + tid;
                const int r = id >> 3, c4 = (id & 7) * 4;
                const float4 v = *reinterpret_cast<const float4*>(Af + (size_t)(row0 + r) * K + k0 + c4);
                uint2 p;
                p.x = pack2(v.x, v.y);
                p.y = pack2(v.z, v.w);
                *reinterpret_cast<uint2*>(&As[r * 40 + c4]) = p;
            }
        } else {
            const bf16* Ab = (const bf16*)A;
#pragma unroll
            for (int u = 0; u < 2; u++) {
                const int id = u * 256 + tid;
                const int r = id >> 2, c8 = (id & 3) * 8;
                const uint4 v = *reinterpret_cast<const uint4*>(Ab + (size_t)(row0 + r) * K + k0 + c8);
                *reinterpret_cast<uint4*>(&As[r * 40 + c8]) = v;
            }
        }
#pragma unroll
        for (int u = 0; u < 2; u++) {
            const int id = u * 256 + tid;
            const int r = id >> 2, c8 = (id & 3) * 8;
            const uint4 v = *reinterpret_cast<const uint4*>(BT + (size_t)(col0 + r) * K + k0 + c8);
            *reinterpret_cast<uint4*>(&Bs[r * 40 + c8]) = v;
        }
        __syncthreads();

        bf16x8 af[4], bfr[4];
#pragma unroll
        for (int i = 0; i < 4; i++)
            af[i] = *reinterpret_cast<const bf16x8*>(&As[(wm + i * 16 + c) * 40 + quad * 8]);
#pragma unroll
        for (int j = 0; j < 4; j++)
            bfr[j] = *reinterpret_cast<const bf16x8*>(&Bs[(wn + j * 16 + c) * 40 + quad * 8]);
#pragma unroll
        for (int i = 0; i < 4; i++)
#pragma unroll
            for (int j = 0; j < 4; j++)
                acc[i][j] = mfma16(af[i], bfr[j], acc[i][j]);
    }

#pragma unroll
    for (int i = 0; i < 4; i++) {
        const int rowb = row0 + wm + i * 16 + quad * 4;
#pragma unroll
        for (int j = 0; j < 4; j++) {
            const int col = col0 + wn + j * 16 + c;
            const float bcol = bias[col];
#pragma unroll
            for (int r = 0; r < 4; r++) {
                float v = acc[i][j][r] + bcol;
                const int rr = rowb + r;
                if (EPI == 0) {
                    ((bf16*)outp)[(size_t)rr * Nout + col] = __float2bfloat16(v);
                } else if (EPI == 1) {
                    const int bb = rr >> 10, m = rr & 1023;
                    ((bf16*)outp)[((size_t)(bb * Nout + col)) * 1024 + m] = __float2bfloat16(v);
                } else {
                    v += resid[(size_t)rr * Nout + col];
                    ((float*)outp)[(size_t)rr * Nout + col] = v;
                }
            }
        }
    }
}

// ---------------- flash attention: S=theta@phi^T * adj, softmax, O=P@g --------
// v3: BOTH tiles staged via global_load_lds (no reg round-trip, no ds_writes).
// phi LDS [32 rows][64 chunks of 16B] (48 valid + 16 pad; over-read lands in
// the adjacent allocated ws buffer, pad never read). Physical chunk p of row r
// holds global chunk p^(r&7); reads apply the same involution (2-way banks,
// free). gts unchanged [192 pair-rows][8 chunks], same XOR scheme, now staged
// by gload_lds with per-lane pre-swizzled source. LDS 56 KB -> 2 blocks/CU
// (same as before). launch_bounds (256,2): round-6 lesson — (256,3) spilled
// the accumulator. SPLIT=2 preferred (round-7: SPLIT=4 only added traffic).
template <int SPLIT>
__global__ __launch_bounds__(256, 2) void flash_attn(
    const bf16* __restrict__ theta, const bf16* __restrict__ phi,
    const bf16* __restrict__ gT, const float* __restrict__ adj,
    bf16* __restrict__ O, float* __restrict__ Sp, float* __restrict__ ml)
{
    __shared__ short phs[32 * 512];    // [32 n][64 chunks], 48 valid
    __shared__ short gts[192 * 64];    // [192 pair-rows][8 x 16B slots]

    const int tid = threadIdx.x;
    const int lane = tid & 63, w = tid >> 6;
    const int quad = lane >> 4, c = lane & 15;
    const int qb = blockIdx.x, b = blockIdx.y;
    const int sp = (SPLIT > 1) ? blockIdx.z : 0;
    constexpr int CH = Nn / SPLIT;
    const int n_lo = sp * CH;

    // preload theta A-frags: 16 q-rows x 384 d per wave
    const size_t thbase = ((size_t)b * Nn + qb * 64 + w * 16 + c) * Dd;
    bf16x8 ath[12];
#pragma unroll
    for (int dq = 0; dq < 12; dq++)
        ath[dq] = *reinterpret_cast<const bf16x8*>(theta + thbase + dq * 32 + quad * 8);

    // swizzled gts read offset: d = dn*16 + c -> pair-row r = dn*8 + (c>>1),
    // slot = (4*(c&1) + quad) ^ ((c>>1)&7)
    const int goff = (c >> 1) * 64 + (((4 * (c & 1) + quad) ^ ((c >> 1) & 7)) * 8);
    // phi chunk XOR for rows c and 16+c (same since 16 == 0 mod 8)
    const int pxor = c & 7;

    // gts staging source precompute: chunk id = w*384 + i*64 + lane
    int gd[6], gcc[6];
#pragma unroll
    for (int i = 0; i < 6; i++) {
        const int id = w * 384 + i * 64 + lane;
        const int r = id >> 3, sl = id & 7;
        const int sg = sl ^ (r & 7);
        gd[i] = 2 * r + (sg >> 2);
        gcc[i] = (sg & 3) * 8;
    }

    const f32x4 fz = {0.f, 0.f, 0.f, 0.f};
    f32x4 o[24];
#pragma unroll
    for (int t = 0; t < 24; t++) o[t] = fz;
    float mrow[4], lrow[4];
#pragma unroll
    for (int r = 0; r < 4; r++) { mrow[r] = -INFINITY; lrow[r] = 0.f; }

    for (int it = 0; it < CH / 32; ++it) {
        const int n0 = n_lo + it * 32;
        __syncthreads();   // (1) prior iteration's LDS reads done
        {   // stage phi rows n0..n0+31 via gload_lds: wave w -> rows w*8+i
            const bf16* src = phi + ((size_t)b * Nn + n0) * Dd;
#pragma unroll
            for (int i = 0; i < 8; i++) {
                const int r = w * 8 + i;
                GLOAD_LDS16(src + (size_t)r * Dd + ((lane ^ (r & 7)) << 3),
                            (char*)phs + r * 1024);
            }
        }
        {   // stage gT[b][d][n0..n0+31] via gload_lds, pre-swizzled source
            const bf16* src = gT + ((size_t)b * Dd) * Nn + n0;
#pragma unroll
            for (int i = 0; i < 6; i++) {
                GLOAD_LDS16(src + (size_t)gd[i] * Nn + gcc[i],
                            (char*)gts + (w * 384 + i * 64) * 16);
            }
        }
        __syncthreads();   // (2) staged data visible (vmcnt drained)

        // S tiles: 16 q x 32 n, accumulate over D=384
        f32x4 s0 = fz, s1 = fz;
#pragma unroll
        for (int dq = 0; dq < 12; dq++) {
            const int ch = ((dq * 4 + quad) ^ pxor) * 8;
            const bf16x8 b0 = *reinterpret_cast<const bf16x8*>(&phs[c * 512 + ch]);
            const bf16x8 b1 = *reinterpret_cast<const bf16x8*>(&phs[(16 + c) * 512 + ch]);
            s0 = mfma16(ath[dq], b0, s0);
            s1 = mfma16(ath[dq], b1, s1);
        }

        // adj multiply + online softmax (C layout: row = quad*4+r, col = c)
        const float* arow = adj + ((size_t)b * Nn + qb * 64 + w * 16 + quad * 4) * Nn + n0;
        float p0[4], p1[4], alpha[4];
#pragma unroll
        for (int r = 0; r < 4; r++) {
            const float v0 = s0[r] * arow[(size_t)r * Nn + c];
            const float v1 = s1[r] * arow[(size_t)r * Nn + 16 + c];
            float t = fmaxf(v0, v1);
#pragma unroll
            for (int msk = 1; msk < 16; msk <<= 1) t = fmaxf(t, __shfl_xor(t, msk));
            const float mn = fmaxf(mrow[r], t);
            alpha[r] = __expf(mrow[r] - mn);
            mrow[r] = mn;
            p0[r] = __expf(v0 - mn);
            p1[r] = __expf(v1 - mn);
            float u = p0[r] + p1[r];
#pragma unroll
            for (int msk = 1; msk < 16; msk <<= 1) u += __shfl_xor(u, msk);
            lrow[r] = lrow[r] * alpha[r] + u;
        }
#pragma unroll
        for (int t = 0; t < 24; t++)
#pragma unroll
            for (int r = 0; r < 4; r++) o[t][r] *= alpha[r];

        __syncthreads();   // (3) all waves done reading phs -> safe to alias
        // P (C layout) -> wave-private region aliased in phs -> A layout
        short* pl = phs + w * 640;   // 16 rows x 40 shorts per wave
#pragma unroll
        for (int r = 0; r < 4; r++) {
            pl[(quad * 4 + r) * 40 + c] = f2b(p0[r]);
            pl[(quad * 4 + r) * 40 + 16 + c] = f2b(p1[r]);
        }
        const bf16x8 ap = *reinterpret_cast<const bf16x8*>(&pl[c * 40 + quad * 8]);
#pragma unroll
        for (int dn = 0; dn < 24; dn++) {
            const bf16x8 bg = *reinterpret_cast<const bf16x8*>(&gts[dn * 512 + goff]);
            o[dn] = mfma16(ap, bg, o[dn]);
        }
    }

    const int rowb = qb * 64 + w * 16 + quad * 4;
    if (SPLIT > 1) {
        float* srow = Sp + ((size_t)sp * Bb * Nn + (size_t)b * Nn + rowb) * Dd;
#pragma unroll
        for (int dn = 0; dn < 24; dn++)
#pragma unroll
            for (int r = 0; r < 4; r++)
                srow[(size_t)r * Dd + dn * 16 + c] = o[dn][r];
        if (c == 0) {
#pragma unroll
            for (int r = 0; r < 4; r++) {
                const size_t rid = (size_t)sp * Bb * Nn + (size_t)b * Nn + rowb + r;
                ml[rid * 2]     = mrow[r];
                ml[rid * 2 + 1] = lrow[r];
            }
        }
    } else {
        float inv[4];
#pragma unroll
        for (int r = 0; r < 4; r++) inv[r] = 1.0f / lrow[r];
        bf16* orow = O + ((size_t)b * Nn + rowb) * Dd;
#pragma unroll
        for (int dn = 0; dn < 24; dn++)
#pragma unroll
            for (int r = 0; r < 4; r++)
                orow[(size_t)r * Dd + dn * 16 + c] = __float2bfloat16(o[dn][r] * inv[r]);
    }
}

// ---------------- combine the NS KV-split partials -> normalized bf16 O ------
template <int NS>
__global__ __launch_bounds__(256) void attn_combine(
    const float* __restrict__ Sp, const float* __restrict__ ml,
    bf16* __restrict__ O)
{
    constexpr size_t M = (size_t)Bb * Nn;
    const size_t idx = (size_t)blockIdx.x * 256 + threadIdx.x;  // x4 elements
    const size_t e0 = idx * 4;
    const size_t row = e0 / Dd;
    float mv[NS], lv[NS];
    float mx = -INFINITY;
#pragma unroll
    for (int i = 0; i < NS; i++) {
        mv[i] = ml[((size_t)i * M + row) * 2];
        lv[i] = ml[((size_t)i * M + row) * 2 + 1];
        mx = fmaxf(mx, mv[i]);
    }
    float wsum = 0.f, wv[NS];
#pragma unroll
    for (int i = 0; i < NS; i++) { wv[i] = __expf(mv[i] - mx); wsum += wv[i] * lv[i]; }
    const float inv = 1.0f / wsum;
    float ax = 0.f, ay = 0.f, az = 0.f, aw = 0.f;
#pragma unroll
    for (int i = 0; i < NS; i++) {
        const float4 a = *reinterpret_cast<const float4*>(Sp + (size_t)i * M * Dd + e0);
        ax += wv[i] * a.x; ay += wv[i] * a.y; az += wv[i] * a.z; aw += wv[i] * a.w;
    }
    uint2 p;
    p.x = pack2(ax * inv, ay * inv);
    p.y = pack2(az * inv, aw * inv);
    *reinterpret_cast<uint2*>(O + e0) = p;
}

// ================== fallback path (proven, needs 25.2 MB ws) =================
__global__ __launch_bounds__(256) void proj_gemm(
    const float* __restrict__ A, const float* __restrict__ W,
    const float* __restrict__ bias, bf16* __restrict__ out,
    int M, int K, int Nd)
{
    __shared__ float Asm[16][65];
    __shared__ float Bsm[16][65];
    const int tid = threadIdx.x;
    const int tx = tid & 15, ty = tid >> 4;
    const int row0 = blockIdx.x * 64, col0 = blockIdx.y * 64;
    float acc[4][4] = {};
    for (int k0 = 0; k0 < K; k0 += 16) {
        {
            const int m = tid >> 2, kq = (tid & 3) * 4;
            const float* p = A + (size_t)(row0 + m) * K + k0 + kq;
#pragma unroll
            for (int j = 0; j < 4; j++) Asm[kq + j][m] = p[j];
        }
        {
            const int k = tid >> 4, n4 = (tid & 15) * 4;
            const float* p = W + (size_t)(k0 + k) * Nd + col0 + n4;
#pragma unroll
            for (int j = 0; j < 4; j++) Bsm[k][n4 + j] = p[j];
        }
        __syncthreads();
#pragma unroll
        for (int k = 0; k < 16; k++) {
            float a[4], bv[4];
#pragma unroll
            for (int j = 0; j < 4; j++) a[j] = Asm[k][ty * 4 + j];
#pragma unroll
            for (int j = 0; j < 4; j++) bv[j] = Bsm[k][tx * 4 + j];
#pragma unroll
            for (int i = 0; i < 4; i++)
#pragma unroll
                for (int j = 0; j < 4; j++) acc[i][j] += a[i] * bv[j];
        }
        __syncthreads();
    }
#pragma unroll
    for (int i = 0; i < 4; i++) {
        const int row = row0 + ty * 4 + i;
#pragma unroll
        for (int j = 0; j < 4; j++) {
            const int col = col0 + tx * 4 + j;
            out[(size_t)row * Nd + col] = __float2bfloat16(acc[i][j] + bias[col]);
        }
    }
}

__global__ __launch_bounds__(256) void fused_attn(
    const float* __restrict__ x, const float* __restrict__ adj,
    const float* __restrict__ W_theta, const float* __restrict__ b_theta,
    const bf16* __restrict__ phi, const bf16* __restrict__ g,
    const float* __restrict__ W_out, const float* __restrict__ b_out,
    float* __restrict__ out)
{
    __shared__ float xs[Cc];
    __shared__ float th[Dd];
    __shared__ float s[Nn];
    __shared__ float Os[Dd];
    __shared__ float red[256];
    const int tid = threadIdx.x;
    const int n = blockIdx.x, b = blockIdx.y;
    const int lane = tid & 63, wave = tid >> 6;
    const size_t row = (size_t)b * Nn + n;
    const size_t baseD = (size_t)b * Nn * Dd;
    for (int c = tid; c < Cc; c += 256) xs[c] = x[row * Cc + c];
    __syncthreads();
    for (int d = tid; d < Dd; d += 256) {
        float acc = b_theta[d];
#pragma unroll 8
        for (int c = 0; c < Cc; c++) acc += xs[c] * W_theta[(size_t)c * Dd + d];
        th[d] = acc;
    }
    __syncthreads();
    for (int m = wave; m < Nn; m += 4) {
        const bf16* prow = phi + baseD + (size_t)m * Dd;
        float partial = 0.f;
#pragma unroll
        for (int j = 0; j < 6; j++) {
            const int d = lane + 64 * j;
            partial += th[d] * b2f(prow[d]);
        }
#pragma unroll
        for (int off = 32; off > 0; off >>= 1) partial += __shfl_down(partial, off);
        if (lane == 0)
            s[m] = partial * adj[(size_t)b * Nn * Nn + (size_t)n * Nn + m];
    }
    __syncthreads();
    float mx = -1e30f;
    for (int i = tid; i < Nn; i += 256) mx = fmaxf(mx, s[i]);
    red[tid] = mx; __syncthreads();
    for (int st = 128; st > 0; st >>= 1) {
        if (tid < st) red[tid] = fmaxf(red[tid], red[tid + st]);
        __syncthreads();
    }
    mx = red[0]; __syncthreads();
    float lsum = 0.f;
    for (int i = tid; i < Nn; i += 256) {
        const float e = __expf(s[i] - mx);
        s[i] = e;
        lsum += e;
    }
    red[tid] = lsum; __syncthreads();
    for (int st = 128; st > 0; st >>= 1) {
        if (tid < st) red[tid] += red[tid + st];
        __syncthreads();
    }
    const float inv = 1.0f / red[0];
    __syncthreads();
    for (int d = tid; d < Dd; d += 256) {
        float acc = 0.f;
#pragma unroll 8
        for (int m = 0; m < Nn; m++) acc += s[m] * b2f(g[baseD + (size_t)m * Dd + d]);
        Os[d] = acc * inv;
    }
    __syncthreads();
    for (int c = tid; c < Cc; c += 256) {
        float acc = b_out[c] + xs[c];
#pragma unroll 8
        for (int d = 0; d < Dd; d++) acc += Os[d] * W_out[(size_t)d * Cc + c];
        out[row * Cc + c] = acc;
    }
}

// ============================== launcher ======================================
extern "C" void kernel_launch(void* const* d_in, const int* in_sizes, int n_in,
                              void* d_out, int out_size, void* d_ws, size_t ws_size,
                              hipStream_t stream)
{
    const float* x       = (const float*)d_in[0];
    const float* adj     = (const float*)d_in[1];
    const float* W_theta = (const float*)d_in[2];
    const float* b_theta = (const float*)d_in[3];
    const float* W_phi   = (const float*)d_in[4];
    const float* b_phi   = (const float*)d_in[5];
    const float* W_g     = (const float*)d_in[6];
    const float* b_g     = (const float*)d_in[7];
    const float* W_out   = (const float*)d_in[8];
    const float* b_out   = (const float*)d_in[9];
    float* out = (float*)d_out;

    const int M = Bb * Nn;                       // 16384
    const size_t SZ  = (size_t)Bb * Nn * Dd;     // 6291456
    const size_t SZX = (size_t)M * Cc;           // 12582912
    const size_t WSZ = (size_t)Cc * Dd;          // 294912
    const size_t NEED_OLD = (4 * WSZ + 4 * SZ) * sizeof(bf16);          // ~50.25 MiB
    const size_t NEED_NEW = (4 * WSZ + 4 * SZ + SZX) * sizeof(bf16)
                          + 1152 * sizeof(float);                        // ~74.3 MiB
    const size_t NEED_S2 = NEED_NEW + (2 * SZ + 4 * (size_t)M) * sizeof(float);

    dim3 blk(256);

    if (ws_size >= NEED_NEW) {
        // ws layout: WtT,WpT,WgT contiguous -> one [1152][768] B matrix;
        // theta,phi,gT contiguous -> EPI=3 writes all three.
        bf16* WtT   = (bf16*)d_ws;
        bf16* WoT   = WtT + 3 * WSZ;
        bf16* theta = WoT + WSZ;
        bf16* phi   = theta + SZ;
        bf16* gT    = phi + SZ;
        bf16* O     = gT + SZ;
        bf16* xb    = O + SZ;
        float* biasP = (float*)(xb + SZX);
        float* Sp    = biasP + 1152;
        float* mlp   = Sp + 2 * SZ;

        cast_bias<<<dim3((unsigned)(SZX / 2048)), blk, 0, stream>>>(
            x, (uint4*)xb, b_theta, b_phi, b_g, biasP);
        transpose_cast3<<<dim3(Dd / 32, Cc / 32, 3), blk, 0, stream>>>(
            W_theta, W_phi, W_g, WtT);
        transpose_cast<<<dim3(Cc / 32, Dd / 32), blk, 0, stream>>>(W_out, WoT, Dd, Cc);

        // fused projections: [16384,768] @ [768,1152] -> theta|phi|gT
        gemm_bf16<3><<<dim3(M / 128, 1152 / 128), blk, 0, stream>>>(
            xb, WtT, biasP, nullptr, theta, Cc, 1152);

        // attention (SPLIT=2; round-7: SPLIT=4 only added traffic)
        if (ws_size >= NEED_S2) {
            flash_attn<2><<<dim3(Nn / 64, Bb, 2), blk, 0, stream>>>(
                theta, phi, gT, adj, nullptr, Sp, mlp);
            attn_combine<2><<<dim3((unsigned)(SZ / 1024)), blk, 0, stream>>>(Sp, mlp, O);
        } else {
            flash_attn<1><<<dim3(Nn / 64, Bb, 1), blk, 0, stream>>>(
                theta, phi, gT, adj, O, nullptr, nullptr);
        }

        // out-projection + bias + residual -> f32
        gemm_bf16<2><<<dim3(M / 128, Cc / 128), blk, 0, stream>>>(
            O, WoT, b_out, x, out, Dd, Cc);
    } else if (ws_size >= NEED_OLD) {
        bf16* WtT   = (bf16*)d_ws;
        bf16* WpT   = WtT + WSZ;
        bf16* WgT   = WtT + 2 * WSZ;
        bf16* WoT   = WtT + 3 * WSZ;
        bf16* theta = WoT + WSZ;
        bf16* phi   = theta + SZ;
        bf16* gT    = phi + SZ;
        bf16* O     = gT + SZ;

        transpose_cast<<<dim3(Dd / 32, Cc / 32), blk, 0, stream>>>(W_theta, WtT, Cc, Dd);
        transpose_cast<<<dim3(Dd / 32, Cc / 32), blk, 0, stream>>>(W_phi,   WpT, Cc, Dd);
        transpose_cast<<<dim3(Dd / 32, Cc / 32), blk, 0, stream>>>(W_g,     WgT, Cc, Dd);
        transpose_cast<<<dim3(Cc / 32, Dd / 32), blk, 0, stream>>>(W_out,   WoT, Dd, Cc);

        dim3 gp(M / 128, Dd / 128);
        gemm_mfma<float, 0><<<gp, blk, 0, stream>>>(x, WtT, b_theta, nullptr, theta, Cc, Dd);
        gemm_mfma<float, 0><<<gp, blk, 0, stream>>>(x, WpT, b_phi,   nullptr, phi,   Cc, Dd);
        gemm_mfma<float, 1><<<gp, blk, 0, stream>>>(x, WgT, b_g,     nullptr, gT,    Cc, Dd);

        flash_attn<1><<<dim3(Nn / 64, Bb, 1), blk, 0, stream>>>(
            theta, phi, gT, adj, O, nullptr, nullptr);

        dim3 go(M / 128, Cc / 128);
        gemm_mfma<bf16, 2><<<go, blk, 0, stream>>>(O, WoT, b_out, x, out, Dd, Cc);
    } else {
        bf16* phi = (bf16*)d_ws;
        bf16* g   = phi + SZ;
        dim3 gproj(M / 64, Dd / 64);
        proj_gemm<<<gproj, blk, 0, stream>>>(x, W_phi, b_phi, phi, M, Cc, Dd);
        proj_gemm<<<gproj, blk, 0, stream>>>(x, W_g, b_g, g, M, Cc, Dd);
        fused_attn<<<dim3(Nn, Bb), blk, 0, stream>>>(
            x, adj, W_theta, b_theta, phi, g, W_out, b_out, out);
    }
}

// Round 11
// 313.445 us; speedup vs baseline: 1.0356x; 1.0356x over previous
//
#include <hip/hip_runtime.h>
#include <hip/hip_bf16.h>

typedef __hip_bfloat16 bf16;
typedef short bf16x8 __attribute__((ext_vector_type(8)));
typedef float f32x4 __attribute__((ext_vector_type(4)));

constexpr int Bb = 16, Nn = 1024, Cc = 768, Dd = 384;

static __device__ __forceinline__ f32x4 mfma16(bf16x8 a, bf16x8 b, f32x4 c) {
    return __builtin_amdgcn_mfma_f32_16x16x32_bf16(a, b, c, 0, 0, 0);
}
static __device__ __forceinline__ short f2b(float v) {
    __hip_bfloat16 h = __float2bfloat16(v);
    return *reinterpret_cast<short*>(&h);
}
static __device__ __forceinline__ unsigned pack2(float lo, float hi) {
    return ((unsigned)(unsigned short)f2b(hi) << 16) | (unsigned short)(unsigned)f2b(lo);
}
static __device__ __forceinline__ float b2f(bf16 x) { return __bfloat162float(x); }

// async 16B global->LDS (gfx950). lds base must be wave-uniform; lane writes
// base + lane*16. global src is per-lane.
#define GLOAD_LDS16(g, l) __builtin_amdgcn_global_load_lds(                    \
    (const __attribute__((address_space(1))) void*)(g),                        \
    (__attribute__((address_space(3))) void*)(l), 16, 0, 0)

// -------- x f32 -> bf16 cast (one pass) + bias concat folded into block 0 ----
__global__ __launch_bounds__(256) void cast_bias(
    const float* __restrict__ in, uint4* __restrict__ out,
    const float* __restrict__ bt, const float* __restrict__ bp,
    const float* __restrict__ bg, float* __restrict__ biasP)
{
    const size_t i = (size_t)blockIdx.x * 256 + threadIdx.x;
    const float4 a = reinterpret_cast<const float4*>(in)[i * 2];
    const float4 b = reinterpret_cast<const float4*>(in)[i * 2 + 1];
    uint4 v;
    v.x = pack2(a.x, a.y);
    v.y = pack2(a.z, a.w);
    v.z = pack2(b.x, b.y);
    v.w = pack2(b.z, b.w);
    out[i] = v;
    if (blockIdx.x == 0) {
        for (int k = threadIdx.x; k < 1152; k += 256)
            biasP[k] = k < 384 ? bt[k] : (k < 768 ? bp[k - 384] : bg[k - 768]);
    }
}

// ---------------- transpose + cast: out[n][k] = (bf16) in[k][n] ---------------
__global__ __launch_bounds__(256) void transpose_cast(
    const float* __restrict__ in, bf16* __restrict__ out, int K, int N)
{
    __shared__ float t[32][33];
    const int n0 = blockIdx.x * 32, k0 = blockIdx.y * 32;
    const int tx = threadIdx.x & 31, ty = threadIdx.x >> 5;
#pragma unroll
    for (int i = 0; i < 4; i++)
        t[ty + i * 8][tx] = in[(size_t)(k0 + ty + i * 8) * N + n0 + tx];
    __syncthreads();
#pragma unroll
    for (int i = 0; i < 4; i++)
        out[(size_t)(n0 + ty + i * 8) * K + k0 + tx] = __float2bfloat16(t[tx][ty + i * 8]);
}

// -------- 3x QKV weight transpose in one launch (blockIdx.z selects) ---------
__global__ __launch_bounds__(256) void transpose_cast3(
    const float* __restrict__ w0, const float* __restrict__ w1,
    const float* __restrict__ w2, bf16* __restrict__ outbase)
{
    __shared__ float t[32][33];
    const float* in = blockIdx.z == 0 ? w0 : (blockIdx.z == 1 ? w1 : w2);
    bf16* out = outbase + (size_t)blockIdx.z * Cc * Dd;
    const int n0 = blockIdx.x * 32, k0 = blockIdx.y * 32;
    const int tx = threadIdx.x & 31, ty = threadIdx.x >> 5;
#pragma unroll
    for (int i = 0; i < 4; i++)
        t[ty + i * 8][tx] = in[(size_t)(k0 + ty + i * 8) * Dd + n0 + tx];
    __syncthreads();
#pragma unroll
    for (int i = 0; i < 4; i++)
        out[(size_t)(n0 + ty + i * 8) * Cc + k0 + tx] = __float2bfloat16(t[tx][ty + i * 8]);
}

// ======= bf16 MFMA GEMM v2: global_load_lds staging, BK=64, XOR swizzle ======
// C = A[M,K] @ BT[N,K]^T + bias. 128x128 tile, 256 threads (4 waves, 64x64).
// LDS linear [128 rows][64 shorts]; slot ch of row r holds global chunk
// ch ^ (r&7). Both-sides swizzle via pre-swizzled per-lane global source.
// EPI: 2 = f32 out with +resid; 3 = fused projection split (theta|phi|gT).
template <int EPI>
__global__ __launch_bounds__(256) void gemm_bf16(
    const bf16* __restrict__ A, const bf16* __restrict__ BT,
    const float* __restrict__ bias, const float* __restrict__ resid,
    void* __restrict__ outp, int K, int Nout)
{
    __shared__ short As[128 * 64];
    __shared__ short Bs[128 * 64];
    const int tid = threadIdx.x;
    const int lane = tid & 63, w = tid >> 6;
    const int quad = lane >> 4, c = lane & 15;
    const int row0 = blockIdx.x * 128, col0 = blockIdx.y * 128;
    const int wm = (w & 1) * 64, wn = (w >> 1) * 64;

    const int rA = w * 32 + (lane >> 3);
    const int cs = (lane & 7) ^ (lane >> 3);
    const bf16* Ag = A  + (size_t)(row0 + rA) * K + cs * 8;
    const bf16* Bg = BT + (size_t)(col0 + rA) * K + cs * 8;
    char* Asb = (char*)As + w * 4096;
    char* Bsb = (char*)Bs + w * 4096;

    const f32x4 fz = {0.f, 0.f, 0.f, 0.f};
    f32x4 acc[4][4];
#pragma unroll
    for (int i = 0; i < 4; i++)
#pragma unroll
        for (int j = 0; j < 4; j++) acc[i][j] = fz;

    for (int k0 = 0; k0 < K; k0 += 64) {
        __syncthreads();
#pragma unroll
        for (int i = 0; i < 4; i++) {
            GLOAD_LDS16(Ag + (size_t)i * 8 * K + k0, Asb + i * 1024);
            GLOAD_LDS16(Bg + (size_t)i * 8 * K + k0, Bsb + i * 1024);
        }
        __syncthreads();   // compiler drains vmcnt before barrier

        bf16x8 af[2][4], bfr[2][4];
#pragma unroll
        for (int kk = 0; kk < 2; kk++) {
#pragma unroll
            for (int i = 0; i < 4; i++) {
                const int r = wm + i * 16 + c;
                const int ch = (kk * 4 + quad) ^ (r & 7);
                af[kk][i] = *reinterpret_cast<const bf16x8*>(&As[r * 64 + ch * 8]);
            }
#pragma unroll
            for (int j = 0; j < 4; j++) {
                const int r = wn + j * 16 + c;
                const int ch = (kk * 4 + quad) ^ (r & 7);
                bfr[kk][j] = *reinterpret_cast<const bf16x8*>(&Bs[r * 64 + ch * 8]);
            }
        }
#pragma unroll
        for (int kk = 0; kk < 2; kk++)
#pragma unroll
            for (int i = 0; i < 4; i++)
#pragma unroll
                for (int j = 0; j < 4; j++)
                    acc[i][j] = mfma16(af[kk][i], bfr[kk][j], acc[i][j]);
    }

    const size_t SZc = (size_t)Bb * Nn * Dd;
#pragma unroll
    for (int i = 0; i < 4; i++) {
        const int rowb = row0 + wm + i * 16 + quad * 4;
#pragma unroll
        for (int j = 0; j < 4; j++) {
            const int col = col0 + wn + j * 16 + c;
            const float bcol = bias[col];
#pragma unroll
            for (int r = 0; r < 4; r++) {
                float v = acc[i][j][r] + bcol;
                const int rr = rowb + r;
                if (EPI == 2) {
                    v += resid[(size_t)rr * Nout + col];
                    ((float*)outp)[(size_t)rr * Nout + col] = v;
                } else {
                    // fused projection: col 0..383 theta, 384..767 phi, 768.. gT
                    const int seg = col / 384;
                    const int cl = col - seg * 384;
                    bf16* base = (bf16*)outp;
                    if (seg < 2) {
                        base[(size_t)seg * SZc + (size_t)rr * Dd + cl] = __float2bfloat16(v);
                    } else {
                        const int bb = rr >> 10, m = rr & 1023;
                        base[2 * SZc + ((size_t)(bb * Dd + cl)) * 1024 + m] = __float2bfloat16(v);
                    }
                }
            }
        }
    }
}

// ---------------- MFMA GEMM v1 (reg-staged) — fallback paths only ------------
template <typename TA, int EPI>
__global__ __launch_bounds__(256) void gemm_mfma(
    const TA* __restrict__ A, const bf16* __restrict__ BT,
    const float* __restrict__ bias, const float* __restrict__ resid,
    void* __restrict__ outp, int K, int Nout)
{
    __shared__ short As[128 * 40];
    __shared__ short Bs[128 * 40];
    const int tid = threadIdx.x;
    const int lane = tid & 63, w = tid >> 6;
    const int quad = lane >> 4, c = lane & 15;
    const int row0 = blockIdx.x * 128, col0 = blockIdx.y * 128;
    const int wm = (w & 1) * 64, wn = (w >> 1) * 64;

    const f32x4 fz = {0.f, 0.f, 0.f, 0.f};
    f32x4 acc[4][4];
#pragma unroll
    for (int i = 0; i < 4; i++)
#pragma unroll
        for (int j = 0; j < 4; j++) acc[i][j] = fz;

    for (int k0 = 0; k0 < K; k0 += 32) {
        __syncthreads();
        if (sizeof(TA) == 4) {
            const float* Af = (const float*)A;
#pragma unroll
            for (int u = 0; u < 4; u++) {
                const int id = u * 256 + tid;
                const int r = id >> 3, c4 = (id & 7) * 4;
                const float4 v = *reinterpret_cast<const float4*>(Af + (size_t)(row0 + r) * K + k0 + c4);
                uint2 p;
                p.x = pack2(v.x, v.y);
                p.y = pack2(v.z, v.w);
                *reinterpret_cast<uint2*>(&As[r * 40 + c4]) = p;
            }
        } else {
            const bf16* Ab = (const bf16*)A;
#pragma unroll
            for (int u = 0; u < 2; u++) {
                const int id = u * 256 + tid;
                const int r = id >> 2, c8 = (id & 3) * 8;
                const uint4 v = *reinterpret_cast<const uint4*>(Ab + (size_t)(row0 + r) * K + k0 + c8);
                *reinterpret_cast<uint4*>(&As[r * 40 + c8]) = v;
            }
        }
#pragma unroll
        for (int u = 0; u < 2; u++) {
            const int id = u * 256 + tid;
            const int r = id >> 2, c8 = (id & 3) * 8;
            const uint4 v = *reinterpret_cast<const uint4*>(BT + (size_t)(col0 + r) * K + k0 + c8);
            *reinterpret_cast<uint4*>(&Bs[r * 40 + c8]) = v;
        }
        __syncthreads();

        bf16x8 af[4], bfr[4];
#pragma unroll
        for (int i = 0; i < 4; i++)
            af[i] = *reinterpret_cast<const bf16x8*>(&As[(wm + i * 16 + c) * 40 + quad * 8]);
#pragma unroll
        for (int j = 0; j < 4; j++)
            bfr[j] = *reinterpret_cast<const bf16x8*>(&Bs[(wn + j * 16 + c) * 40 + quad * 8]);
#pragma unroll
        for (int i = 0; i < 4; i++)
#pragma unroll
            for (int j = 0; j < 4; j++)
                acc[i][j] = mfma16(af[i], bfr[j], acc[i][j]);
    }

#pragma unroll
    for (int i = 0; i < 4; i++) {
        const int rowb = row0 + wm + i * 16 + quad * 4;
#pragma unroll
        for (int j = 0; j < 4; j++) {
            const int col = col0 + wn + j * 16 + c;
            const float bcol = bias[col];
#pragma unroll
            for (int r = 0; r < 4; r++) {
                float v = acc[i][j][r] + bcol;
                const int rr = rowb + r;
                if (EPI == 0) {
                    ((bf16*)outp)[(size_t)rr * Nout + col] = __float2bfloat16(v);
                } else if (EPI == 1) {
                    const int bb = rr >> 10, m = rr & 1023;
                    ((bf16*)outp)[((size_t)(bb * Nout + col)) * 1024 + m] = __float2bfloat16(v);
                } else {
                    v += resid[(size_t)rr * Nout + col];
                    ((float*)outp)[(size_t)rr * Nout + col] = v;
                }
            }
        }
    }
}

// ---------------- flash attention: S=theta@phi^T * adj, softmax, O=P@g --------
// v4: 8 waves (512 threads) x 16 Q-rows = 128 q-rows per block. Same 56 KB LDS
// tile now feeds 2x the q-rows -> per-CU staging bytes per unit compute HALVE
// (round-9 model: flash is staging-bandwidth-bound per CU, not issue-bound —
// gload_lds conversion was NULL at 85us). grid (Nn/128, Bb, SPLIT) = 256
// blocks at SPLIT=2 -> 1 block/CU x 8 waves (2/SIMD, same as before).
// Per-wave footprint unchanged (o[24]+ath[12], VGPR ~128);
// __launch_bounds__(512,2) keeps the 256-reg cap (round-6: min-waves 3
// spilled the accumulator). Staging split 7 gload_lds/wave (phi 4, gts 3).
template <int SPLIT>
__global__ __launch_bounds__(512, 2) void flash_attn(
    const bf16* __restrict__ theta, const bf16* __restrict__ phi,
    const bf16* __restrict__ gT, const float* __restrict__ adj,
    bf16* __restrict__ O, float* __restrict__ Sp, float* __restrict__ ml)
{
    __shared__ short phs[32 * 512];    // [32 n][64 chunks of 16B], 48 valid
    __shared__ short gts[192 * 64];    // [192 pair-rows][8 x 16B slots]

    const int tid = threadIdx.x;
    const int lane = tid & 63, w = tid >> 6;       // w in [0,8)
    const int quad = lane >> 4, c = lane & 15;
    const int qb = blockIdx.x, b = blockIdx.y;
    const int sp = (SPLIT > 1) ? blockIdx.z : 0;
    constexpr int CH = Nn / SPLIT;
    const int n_lo = sp * CH;

    // preload theta A-frags: 16 q-rows x 384 d per wave (rows qb*128 + w*16 +)
    const size_t thbase = ((size_t)b * Nn + qb * 128 + w * 16 + c) * Dd;
    bf16x8 ath[12];
#pragma unroll
    for (int dq = 0; dq < 12; dq++)
        ath[dq] = *reinterpret_cast<const bf16x8*>(theta + thbase + dq * 32 + quad * 8);

    // swizzled gts read offset: d = dn*16 + c -> pair-row r = dn*8 + (c>>1),
    // slot = (4*(c&1) + quad) ^ ((c>>1)&7)
    const int goff = (c >> 1) * 64 + (((4 * (c & 1) + quad) ^ ((c >> 1) & 7)) * 8);
    // phi chunk XOR for rows c and 16+c (same since 16 == 0 mod 8)
    const int pxor = c & 7;

    // gts staging source precompute: wave w stages segments w*3+i (i<3),
    // chunk id = (w*3+i)*64 + lane
    int gd[3], gcc[3];
#pragma unroll
    for (int i = 0; i < 3; i++) {
        const int id = (w * 3 + i) * 64 + lane;
        const int r = id >> 3, sl = id & 7;
        const int sg = sl ^ (r & 7);
        gd[i] = 2 * r + (sg >> 2);
        gcc[i] = (sg & 3) * 8;
    }

    const f32x4 fz = {0.f, 0.f, 0.f, 0.f};
    f32x4 o[24];
#pragma unroll
    for (int t = 0; t < 24; t++) o[t] = fz;
    float mrow[4], lrow[4];
#pragma unroll
    for (int r = 0; r < 4; r++) { mrow[r] = -INFINITY; lrow[r] = 0.f; }

    for (int it = 0; it < CH / 32; ++it) {
        const int n0 = n_lo + it * 32;
        __syncthreads();   // (1) prior iteration's LDS reads done
        {   // stage phi rows n0..n0+31 via gload_lds: wave w -> rows w*4+i
            const bf16* src = phi + ((size_t)b * Nn + n0) * Dd;
#pragma unroll
            for (int i = 0; i < 4; i++) {
                const int r = w * 4 + i;
                GLOAD_LDS16(src + (size_t)r * Dd + ((lane ^ (r & 7)) << 3),
                            (char*)phs + r * 1024);
            }
        }
        {   // stage gT[b][d][n0..n0+31] via gload_lds, pre-swizzled source
            const bf16* src = gT + ((size_t)b * Dd) * Nn + n0;
#pragma unroll
            for (int i = 0; i < 3; i++) {
                GLOAD_LDS16(src + (size_t)gd[i] * Nn + gcc[i],
                            (char*)gts + (w * 3 + i) * 1024);
            }
        }
        __syncthreads();   // (2) staged data visible (vmcnt drained)

        // S tiles: 16 q x 32 n, accumulate over D=384
        f32x4 s0 = fz, s1 = fz;
#pragma unroll
        for (int dq = 0; dq < 12; dq++) {
            const int ch = ((dq * 4 + quad) ^ pxor) * 8;
            const bf16x8 b0 = *reinterpret_cast<const bf16x8*>(&phs[c * 512 + ch]);
            const bf16x8 b1 = *reinterpret_cast<const bf16x8*>(&phs[(16 + c) * 512 + ch]);
            s0 = mfma16(ath[dq], b0, s0);
            s1 = mfma16(ath[dq], b1, s1);
        }

        // adj multiply + online softmax (C layout: row = quad*4+r, col = c)
        const float* arow = adj + ((size_t)b * Nn + qb * 128 + w * 16 + quad * 4) * Nn + n0;
        float p0[4], p1[4], alpha[4];
#pragma unroll
        for (int r = 0; r < 4; r++) {
            const float v0 = s0[r] * arow[(size_t)r * Nn + c];
            const float v1 = s1[r] * arow[(size_t)r * Nn + 16 + c];
            float t = fmaxf(v0, v1);
#pragma unroll
            for (int msk = 1; msk < 16; msk <<= 1) t = fmaxf(t, __shfl_xor(t, msk));
            const float mn = fmaxf(mrow[r], t);
            alpha[r] = __expf(mrow[r] - mn);
            mrow[r] = mn;
            p0[r] = __expf(v0 - mn);
            p1[r] = __expf(v1 - mn);
            float u = p0[r] + p1[r];
#pragma unroll
            for (int msk = 1; msk < 16; msk <<= 1) u += __shfl_xor(u, msk);
            lrow[r] = lrow[r] * alpha[r] + u;
        }
#pragma unroll
        for (int t = 0; t < 24; t++)
#pragma unroll
            for (int r = 0; r < 4; r++) o[t][r] *= alpha[r];

        __syncthreads();   // (3) all waves done reading phs -> safe to alias
        // P (C layout) -> wave-private region aliased in phs -> A layout
        short* pl = phs + w * 640;   // 16 rows x 40 shorts per wave (8*640<16384)
#pragma unroll
        for (int r = 0; r < 4; r++) {
            pl[(quad * 4 + r) * 40 + c] = f2b(p0[r]);
            pl[(quad * 4 + r) * 40 + 16 + c] = f2b(p1[r]);
        }
        const bf16x8 ap = *reinterpret_cast<const bf16x8*>(&pl[c * 40 + quad * 8]);
#pragma unroll
        for (int dn = 0; dn < 24; dn++) {
            const bf16x8 bg = *reinterpret_cast<const bf16x8*>(&gts[dn * 512 + goff]);
            o[dn] = mfma16(ap, bg, o[dn]);
        }
    }

    const int rowb = qb * 128 + w * 16 + quad * 4;
    if (SPLIT > 1) {
        float* srow = Sp + ((size_t)sp * Bb * Nn + (size_t)b * Nn + rowb) * Dd;
#pragma unroll
        for (int dn = 0; dn < 24; dn++)
#pragma unroll
            for (int r = 0; r < 4; r++)
                srow[(size_t)r * Dd + dn * 16 + c] = o[dn][r];
        if (c == 0) {
#pragma unroll
            for (int r = 0; r < 4; r++) {
                const size_t rid = (size_t)sp * Bb * Nn + (size_t)b * Nn + rowb + r;
                ml[rid * 2]     = mrow[r];
                ml[rid * 2 + 1] = lrow[r];
            }
        }
    } else {
        float inv[4];
#pragma unroll
        for (int r = 0; r < 4; r++) inv[r] = 1.0f / lrow[r];
        bf16* orow = O + ((size_t)b * Nn + rowb) * Dd;
#pragma unroll
        for (int dn = 0; dn < 24; dn++)
#pragma unroll
            for (int r = 0; r < 4; r++)
                orow[(size_t)r * Dd + dn * 16 + c] = __float2bfloat16(o[dn][r] * inv[r]);
    }
}

// ---------------- combine the NS KV-split partials -> normalized bf16 O ------
template <int NS>
__global__ __launch_bounds__(256) void attn_combine(
    const float* __restrict__ Sp, const float* __restrict__ ml,
    bf16* __restrict__ O)
{
    constexpr size_t M = (size_t)Bb * Nn;
    const size_t idx = (size_t)blockIdx.x * 256 + threadIdx.x;  // x4 elements
    const size_t e0 = idx * 4;
    const size_t row = e0 / Dd;
    float mv[NS], lv[NS];
    float mx = -INFINITY;
#pragma unroll
    for (int i = 0; i < NS; i++) {
        mv[i] = ml[((size_t)i * M + row) * 2];
        lv[i] = ml[((size_t)i * M + row) * 2 + 1];
        mx = fmaxf(mx, mv[i]);
    }
    float wsum = 0.f, wv[NS];
#pragma unroll
    for (int i = 0; i < NS; i++) { wv[i] = __expf(mv[i] - mx); wsum += wv[i] * lv[i]; }
    const float inv = 1.0f / wsum;
    float ax = 0.f, ay = 0.f, az = 0.f, aw = 0.f;
#pragma unroll
    for (int i = 0; i < NS; i++) {
        const float4 a = *reinterpret_cast<const float4*>(Sp + (size_t)i * M * Dd + e0);
        ax += wv[i] * a.x; ay += wv[i] * a.y; az += wv[i] * a.z; aw += wv[i] * a.w;
    }
    uint2 p;
    p.x = pack2(ax * inv, ay * inv);
    p.y = pack2(az * inv, aw * inv);
    *reinterpret_cast<uint2*>(O + e0) = p;
}

// ================== fallback path (proven, needs 25.2 MB ws) =================
__global__ __launch_bounds__(256) void proj_gemm(
    const float* __restrict__ A, const float* __restrict__ W,
    const float* __restrict__ bias, bf16* __restrict__ out,
    int M, int K, int Nd)
{
    __shared__ float Asm[16][65];
    __shared__ float Bsm[16][65];
    const int tid = threadIdx.x;
    const int tx = tid & 15, ty = tid >> 4;
    const int row0 = blockIdx.x * 64, col0 = blockIdx.y * 64;
    float acc[4][4] = {};
    for (int k0 = 0; k0 < K; k0 += 16) {
        {
            const int m = tid >> 2, kq = (tid & 3) * 4;
            const float* p = A + (size_t)(row0 + m) * K + k0 + kq;
#pragma unroll
            for (int j = 0; j < 4; j++) Asm[kq + j][m] = p[j];
        }
        {
            const int k = tid >> 4, n4 = (tid & 15) * 4;
            const float* p = W + (size_t)(k0 + k) * Nd + col0 + n4;
#pragma unroll
            for (int j = 0; j < 4; j++) Bsm[k][n4 + j] = p[j];
        }
        __syncthreads();
#pragma unroll
        for (int k = 0; k < 16; k++) {
            float a[4], bv[4];
#pragma unroll
            for (int j = 0; j < 4; j++) a[j] = Asm[k][ty * 4 + j];
#pragma unroll
            for (int j = 0; j < 4; j++) bv[j] = Bsm[k][tx * 4 + j];
#pragma unroll
            for (int i = 0; i < 4; i++)
#pragma unroll
                for (int j = 0; j < 4; j++) acc[i][j] += a[i] * bv[j];
        }
        __syncthreads();
    }
#pragma unroll
    for (int i = 0; i < 4; i++) {
        const int row = row0 + ty * 4 + i;
#pragma unroll
        for (int j = 0; j < 4; j++) {
            const int col = col0 + tx * 4 + j;
            out[(size_t)row * Nd + col] = __float2bfloat16(acc[i][j] + bias[col]);
        }
    }
}

__global__ __launch_bounds__(256) void fused_attn(
    const float* __restrict__ x, const float* __restrict__ adj,
    const float* __restrict__ W_theta, const float* __restrict__ b_theta,
    const bf16* __restrict__ phi, const bf16* __restrict__ g,
    const float* __restrict__ W_out, const float* __restrict__ b_out,
    float* __restrict__ out)
{
    __shared__ float xs[Cc];
    __shared__ float th[Dd];
    __shared__ float s[Nn];
    __shared__ float Os[Dd];
    __shared__ float red[256];
    const int tid = threadIdx.x;
    const int n = blockIdx.x, b = blockIdx.y;
    const int lane = tid & 63, wave = tid >> 6;
    const size_t row = (size_t)b * Nn + n;
    const size_t baseD = (size_t)b * Nn * Dd;
    for (int c = tid; c < Cc; c += 256) xs[c] = x[row * Cc + c];
    __syncthreads();
    for (int d = tid; d < Dd; d += 256) {
        float acc = b_theta[d];
#pragma unroll 8
        for (int c = 0; c < Cc; c++) acc += xs[c] * W_theta[(size_t)c * Dd + d];
        th[d] = acc;
    }
    __syncthreads();
    for (int m = wave; m < Nn; m += 4) {
        const bf16* prow = phi + baseD + (size_t)m * Dd;
        float partial = 0.f;
#pragma unroll
        for (int j = 0; j < 6; j++) {
            const int d = lane + 64 * j;
            partial += th[d] * b2f(prow[d]);
        }
#pragma unroll
        for (int off = 32; off > 0; off >>= 1) partial += __shfl_down(partial, off);
        if (lane == 0)
            s[m] = partial * adj[(size_t)b * Nn * Nn + (size_t)n * Nn + m];
    }
    __syncthreads();
    float mx = -1e30f;
    for (int i = tid; i < Nn; i += 256) mx = fmaxf(mx, s[i]);
    red[tid] = mx; __syncthreads();
    for (int st = 128; st > 0; st >>= 1) {
        if (tid < st) red[tid] = fmaxf(red[tid], red[tid + st]);
        __syncthreads();
    }
    mx = red[0]; __syncthreads();
    float lsum = 0.f;
    for (int i = tid; i < Nn; i += 256) {
        const float e = __expf(s[i] - mx);
        s[i] = e;
        lsum += e;
    }
    red[tid] = lsum; __syncthreads();
    for (int st = 128; st > 0; st >>= 1) {
        if (tid < st) red[tid] += red[tid + st];
        __syncthreads();
    }
    const float inv = 1.0f / red[0];
    __syncthreads();
    for (int d = tid; d < Dd; d += 256) {
        float acc = 0.f;
#pragma unroll 8
        for (int m = 0; m < Nn; m++) acc += s[m] * b2f(g[baseD + (size_t)m * Dd + d]);
        Os[d] = acc * inv;
    }
    __syncthreads();
    for (int c = tid; c < Cc; c += 256) {
        float acc = b_out[c] + xs[c];
#pragma unroll 8
        for (int d = 0; d < Dd; d++) acc += Os[d] * W_out[(size_t)d * Cc + c];
        out[row * Cc + c] = acc;
    }
}

// ============================== launcher ======================================
extern "C" void kernel_launch(void* const* d_in, const int* in_sizes, int n_in,
                              void* d_out, int out_size, void* d_ws, size_t ws_size,
                              hipStream_t stream)
{
    const float* x       = (const float*)d_in[0];
    const float* adj     = (const float*)d_in[1];
    const float* W_theta = (const float*)d_in[2];
    const float* b_theta = (const float*)d_in[3];
    const float* W_phi   = (const float*)d_in[4];
    const float* b_phi   = (const float*)d_in[5];
    const float* W_g     = (const float*)d_in[6];
    const float* b_g     = (const float*)d_in[7];
    const float* W_out   = (const float*)d_in[8];
    const float* b_out   = (const float*)d_in[9];
    float* out = (float*)d_out;

    const int M = Bb * Nn;                       // 16384
    const size_t SZ  = (size_t)Bb * Nn * Dd;     // 6291456
    const size_t SZX = (size_t)M * Cc;           // 12582912
    const size_t WSZ = (size_t)Cc * Dd;          // 294912
    const size_t NEED_OLD = (4 * WSZ + 4 * SZ) * sizeof(bf16);          // ~50.25 MiB
    const size_t NEED_NEW = (4 * WSZ + 4 * SZ + SZX) * sizeof(bf16)
                          + 1152 * sizeof(float);                        // ~74.3 MiB
    const size_t NEED_S2 = NEED_NEW + (2 * SZ + 4 * (size_t)M) * sizeof(float);

    dim3 blk(256);
    dim3 blk512(512);

    if (ws_size >= NEED_NEW) {
        // ws layout: WtT,WpT,WgT contiguous -> one [1152][768] B matrix;
        // theta,phi,gT contiguous -> EPI=3 writes all three.
        bf16* WtT   = (bf16*)d_ws;
        bf16* WoT   = WtT + 3 * WSZ;
        bf16* theta = WoT + WSZ;
        bf16* phi   = theta + SZ;
        bf16* gT    = phi + SZ;
        bf16* O     = gT + SZ;
        bf16* xb    = O + SZ;
        float* biasP = (float*)(xb + SZX);
        float* Sp    = biasP + 1152;
        float* mlp   = Sp + 2 * SZ;

        cast_bias<<<dim3((unsigned)(SZX / 2048)), blk, 0, stream>>>(
            x, (uint4*)xb, b_theta, b_phi, b_g, biasP);
        transpose_cast3<<<dim3(Dd / 32, Cc / 32, 3), blk, 0, stream>>>(
            W_theta, W_phi, W_g, WtT);
        transpose_cast<<<dim3(Cc / 32, Dd / 32), blk, 0, stream>>>(W_out, WoT, Dd, Cc);

        // fused projections: [16384,768] @ [768,1152] -> theta|phi|gT
        gemm_bf16<3><<<dim3(M / 128, 1152 / 128), blk, 0, stream>>>(
            xb, WtT, biasP, nullptr, theta, Cc, 1152);

        // attention: 8-wave blocks, 128 q-rows each; SPLIT=2
        if (ws_size >= NEED_S2) {
            flash_attn<2><<<dim3(Nn / 128, Bb, 2), blk512, 0, stream>>>(
                theta, phi, gT, adj, nullptr, Sp, mlp);
            attn_combine<2><<<dim3((unsigned)(SZ / 1024)), blk, 0, stream>>>(Sp, mlp, O);
        } else {
            flash_attn<1><<<dim3(Nn / 128, Bb, 1), blk512, 0, stream>>>(
                theta, phi, gT, adj, O, nullptr, nullptr);
        }

        // out-projection + bias + residual -> f32
        gemm_bf16<2><<<dim3(M / 128, Cc / 128), blk, 0, stream>>>(
            O, WoT, b_out, x, out, Dd, Cc);
    } else if (ws_size >= NEED_OLD) {
        bf16* WtT   = (bf16*)d_ws;
        bf16* WpT   = WtT + WSZ;
        bf16* WgT   = WtT + 2 * WSZ;
        bf16* WoT   = WtT + 3 * WSZ;
        bf16* theta = WoT + WSZ;
        bf16* phi   = theta + SZ;
        bf16* gT    = phi + SZ;
        bf16* O     = gT + SZ;

        transpose_cast<<<dim3(Dd / 32, Cc / 32), blk, 0, stream>>>(W_theta, WtT, Cc, Dd);
        transpose_cast<<<dim3(Dd / 32, Cc / 32), blk, 0, stream>>>(W_phi,   WpT, Cc, Dd);
        transpose_cast<<<dim3(Dd / 32, Cc / 32), blk, 0, stream>>>(W_g,     WgT, Cc, Dd);
        transpose_cast<<<dim3(Cc / 32, Dd / 32), blk, 0, stream>>>(W_out,   WoT, Dd, Cc);

        dim3 gp(M / 128, Dd / 128);
        gemm_mfma<float, 0><<<gp, blk, 0, stream>>>(x, WtT, b_theta, nullptr, theta, Cc, Dd);
        gemm_mfma<float, 0><<<gp, blk, 0, stream>>>(x, WpT, b_phi,   nullptr, phi,   Cc, Dd);
        gemm_mfma<float, 1><<<gp, blk, 0, stream>>>(x, WgT, b_g,     nullptr, gT,    Cc, Dd);

        flash_attn<1><<<dim3(Nn / 128, Bb, 1), blk512, 0, stream>>>(
            theta, phi, gT, adj, O, nullptr, nullptr);

        dim3 go(M / 128, Cc / 128);
        gemm_mfma<bf16, 2><<<go, blk, 0, stream>>>(O, WoT, b_out, x, out, Dd, Cc);
    } else {
        bf16* phi = (bf16*)d_ws;
        bf16* g   = phi + SZ;
        dim3 gproj(M / 64, Dd / 64);
        proj_gemm<<<gproj, blk, 0, stream>>>(x, W_phi, b_phi, phi, M, Cc, Dd);
        proj_gemm<<<gproj, blk, 0, stream>>>(x, W_g, b_g, g, M, Cc, Dd);
        fused_attn<<<dim3(Nn, Bb), blk, 0, stream>>>(
            x, adj, W_theta, b_theta, phi, g, W_out, b_out, out);
    }
}